// Round 1
// baseline (5412.787 us; speedup 1.0000x reference)
//
#include <hip/hip_runtime.h>

#define E_EXP 4
#define D_MODEL 1024
#define B_BATCH 4
#define S_SEQ 4096
#define NTOK (B_BATCH*S_SEQ)   // 16384
#define CHUNK 32
#define NCHUNK (S_SEQ/CHUNK)   // 128

typedef float f4 __attribute__((ext_vector_type(4)));

__device__ __forceinline__ unsigned short f2b(float f){
  union{float f;unsigned u;}v; v.f=f;
  unsigned r = v.u + 0x7fffu + ((v.u>>16)&1u);
  return (unsigned short)(r>>16);
}
__device__ __forceinline__ float b2f_lo(unsigned v){ union{unsigned u;float f;}x; x.u=v<<16; return x.f; }
__device__ __forceinline__ float b2f_hi(unsigned v){ union{unsigned u;float f;}x; x.u=v&0xffff0000u; return x.f; }

// ---------------- router: top-2 softmax gate weights per token ----------------
__global__ __launch_bounds__(256) void router_kernel(
    const float* __restrict__ x, const float* __restrict__ Wgate,
    float* __restrict__ wtok)
{
  int gtid = blockIdx.x*256 + threadIdx.x;
  int tok  = gtid >> 6;            // one wave per token
  int lane = threadIdx.x & 63;
  const float* xr = x + (size_t)tok * D_MODEL;
  float acc0=0.f,acc1=0.f,acc2=0.f,acc3=0.f;
  for (int k=lane;k<D_MODEL;k+=64){
    float xv = xr[k];
    acc0 += xv*Wgate[0*D_MODEL+k];
    acc1 += xv*Wgate[1*D_MODEL+k];
    acc2 += xv*Wgate[2*D_MODEL+k];
    acc3 += xv*Wgate[3*D_MODEL+k];
  }
  #pragma unroll
  for (int off=32;off>0;off>>=1){
    acc0 += __shfl_down(acc0,off);
    acc1 += __shfl_down(acc1,off);
    acc2 += __shfl_down(acc2,off);
    acc3 += __shfl_down(acc3,off);
  }
  if (lane==0){
    float l[4]={acc0,acc1,acc2,acc3};
    int i1=0;
    #pragma unroll
    for(int e=1;e<4;e++) if (l[e]>l[i1]) i1=e;   // strict > keeps lowest index on ties (lax.top_k)
    int i2=-1;
    #pragma unroll
    for(int e=0;e<4;e++){ if(e==i1) continue; if(i2<0||l[e]>l[i2]) i2=e; }
    float ex = __expf(l[i2]-l[i1]);
    float w1 = 1.f/(1.f+ex);
    float w2 = ex/(1.f+ex);
    float w[4]={0.f,0.f,0.f,0.f};
    w[i1]=w1; w[i2]=w2;
    float* wp = wtok + (size_t)tok*E_EXP;
    wp[0]=w[0]; wp[1]=w[1]; wp[2]=w[2]; wp[3]=w[3];
  }
}

// ---------------- fp32 tiled GEMM: g,v projections + fused activation -> bf16 xs ----------------
#define TM 64
#define TN 64
#define TK 32

__global__ __launch_bounds__(256) void gemm_gv(
    const float* __restrict__ x,
    const float* __restrict__ Wg, const float* __restrict__ bg,
    const float* __restrict__ Wv, const float* __restrict__ bv,
    unsigned short* __restrict__ xs_out, int e0)
{
  __shared__ __align__(16) float sX[TK][TM+4];
  __shared__ __align__(16) float sG[TK][TN+4];
  __shared__ __align__(16) float sV[TK][TN+4];
  int mtile = blockIdx.x, ntile = blockIdx.y, le = blockIdx.z;
  int e = e0 + le;
  int tid = threadIdx.x;
  int mbase = mtile*TM, nbase = ntile*TN;
  const float* Wge = Wg + (size_t)e*D_MODEL*D_MODEL;
  const float* Wve = Wv + (size_t)e*D_MODEL*D_MODEL;
  float accG[4][4]={}, accV[4][4]={};
  int tx = tid & 15, ty = tid >> 4;
  int m0 = ty*4, n0 = tx*4;
  for (int k0=0;k0<D_MODEL;k0+=TK){
    #pragma unroll
    for (int l=0;l<2;l++){
      int f = tid + l*256;     // 0..511 -> (row, k-quad)
      int r = f>>3;
      int kq = (f&7)*4;
      f4 xv = *(const f4*)&x  [(size_t)(mbase+r)*D_MODEL + k0 + kq];
      f4 gv = *(const f4*)&Wge[(size_t)(nbase+r)*D_MODEL + k0 + kq];
      f4 vv = *(const f4*)&Wve[(size_t)(nbase+r)*D_MODEL + k0 + kq];
      #pragma unroll
      for (int j=0;j<4;j++){ sX[kq+j][r]=xv[j]; sG[kq+j][r]=gv[j]; sV[kq+j][r]=vv[j]; }
    }
    __syncthreads();
    #pragma unroll
    for (int k=0;k<TK;k++){
      f4 xa = *(const f4*)&sX[k][m0];
      f4 ga = *(const f4*)&sG[k][n0];
      f4 va = *(const f4*)&sV[k][n0];
      #pragma unroll
      for (int i=0;i<4;i++)
        #pragma unroll
        for (int j=0;j<4;j++){
          accG[i][j] += xa[i]*ga[j];
          accV[i][j] += xa[i]*va[j];
        }
    }
    __syncthreads();
  }
  #pragma unroll
  for (int i=0;i<4;i++){
    int m = mbase + m0 + i;
    unsigned short tmp[4];
    #pragma unroll
    for (int j=0;j<4;j++){
      int n = nbase + n0 + j;
      float g = accG[i][j] + bg[e*D_MODEL + n];
      float v = accV[i][j] + bv[e*D_MODEL + n];
      float sg = 1.f/(1.f+__expf(-g));
      float th = 1.f - 2.f/(__expf(2.f*v)+1.f);   // tanh(v)
      tmp[j] = f2b(sg*th);
    }
    ushort4 pack; pack.x=tmp[0]; pack.y=tmp[1]; pack.z=tmp[2]; pack.w=tmp[3];
    *(ushort4*)&xs_out[((size_t)le*NTOK + m)*D_MODEL + nbase + n0] = pack;
  }
}

// ---------------- fp32 tiled GEMM: d projection -> bf16 decay a ----------------
__global__ __launch_bounds__(256) void gemm_d(
    const float* __restrict__ x,
    const float* __restrict__ Wd, const float* __restrict__ bd,
    unsigned short* __restrict__ a_out, int e0)
{
  __shared__ __align__(16) float sX[TK][TM+4];
  __shared__ __align__(16) float sD[TK][TN+4];
  int mtile = blockIdx.x, ntile = blockIdx.y, le = blockIdx.z;
  int e = e0 + le;
  int tid = threadIdx.x;
  int mbase = mtile*TM, nbase = ntile*TN;
  const float* Wde = Wd + (size_t)e*D_MODEL*D_MODEL;
  float accD[4][4]={};
  int tx = tid & 15, ty = tid >> 4;
  int m0 = ty*4, n0 = tx*4;
  for (int k0=0;k0<D_MODEL;k0+=TK){
    #pragma unroll
    for (int l=0;l<2;l++){
      int f = tid + l*256;
      int r = f>>3;
      int kq = (f&7)*4;
      f4 xv = *(const f4*)&x  [(size_t)(mbase+r)*D_MODEL + k0 + kq];
      f4 dv = *(const f4*)&Wde[(size_t)(nbase+r)*D_MODEL + k0 + kq];
      #pragma unroll
      for (int j=0;j<4;j++){ sX[kq+j][r]=xv[j]; sD[kq+j][r]=dv[j]; }
    }
    __syncthreads();
    #pragma unroll
    for (int k=0;k<TK;k++){
      f4 xa = *(const f4*)&sX[k][m0];
      f4 da = *(const f4*)&sD[k][n0];
      #pragma unroll
      for (int i=0;i<4;i++)
        #pragma unroll
        for (int j=0;j<4;j++)
          accD[i][j] += xa[i]*da[j];
    }
    __syncthreads();
  }
  #pragma unroll
  for (int i=0;i<4;i++){
    int m = mbase + m0 + i;
    unsigned short tmp[4];
    #pragma unroll
    for (int j=0;j<4;j++){
      int n = nbase + n0 + j;
      float d = accD[i][j] + bd[e*D_MODEL + n];
      float sg = 1.f/(1.f+__expf(-d));
      tmp[j] = f2b(0.001f + 0.998f*sg);
    }
    ushort4 pack; pack.x=tmp[0]; pack.y=tmp[1]; pack.z=tmp[2]; pack.w=tmp[3];
    *(ushort4*)&a_out[((size_t)le*NTOK + m)*D_MODEL + nbase + n0] = pack;
  }
}

// ---------------- chunked scan pass 1: local scan per chunk -> (P, U) ----------------
__global__ __launch_bounds__(512) void scan_pass1(
    const unsigned short* __restrict__ xs, const unsigned short* __restrict__ aa,
    float* __restrict__ P, float* __restrict__ U)
{
  int blk = blockIdx.x;
  int c  = blk % NCHUNK;
  int b  = (blk / NCHUNK) % B_BATCH;
  int le = blk / (NCHUNK*B_BATCH);
  int d0 = threadIdx.x*2;   // 512 threads * 2 channels = 1024 = D
  size_t base = (((size_t)(le*B_BATCH + b))*S_SEQ + (size_t)c*CHUNK)*D_MODEL + d0;
  float h0=0.f,h1=0.f,p0=1.f,p1=1.f;
  #pragma unroll 4
  for (int t=0;t<CHUNK;t++){
    unsigned av = *(const unsigned*)(aa + base);
    unsigned xv = *(const unsigned*)(xs + base);
    float a0=b2f_lo(av), a1=b2f_hi(av);
    float x0=b2f_lo(xv), x1=b2f_hi(xv);
    h0 = a0*h0 + x0; h1 = a1*h1 + x1;
    p0 *= a0; p1 *= a1;
    base += D_MODEL;
  }
  size_t sidx = (((size_t)(le*B_BATCH + b))*NCHUNK + c)*D_MODEL + d0;
  P[sidx]=p0; P[sidx+1]=p1;
  U[sidx]=h0; U[sidx+1]=h1;
}

// ---------------- pass 2: sequential combine over chunks -> Hinit per chunk ----------------
__global__ __launch_bounds__(256) void scan_pass2(
    const float* __restrict__ P, const float* __restrict__ U, float* __restrict__ Hinit)
{
  int ch = blockIdx.x*256 + threadIdx.x;   // (le*B+b, d)
  int d  = ch & (D_MODEL-1);
  int eb = ch >> 10;
  size_t base = (size_t)eb*NCHUNK*D_MODEL + d;
  float H=0.f;
  for (int c=0;c<NCHUNK;c++){
    size_t idx = base + (size_t)c*D_MODEL;
    Hinit[idx] = H;          // state entering chunk c
    H = P[idx]*H + U[idx];
  }
}

// ---------------- pass 3: re-scan with true init + fused top-2 weighted combine ----------------
template<int G>
__global__ __launch_bounds__(512) void scan_pass3(
    const unsigned short* __restrict__ xs, const unsigned short* __restrict__ aa,
    const float* __restrict__ Hinit, const float* __restrict__ wtok,
    float* __restrict__ out, int e0)
{
  int blk = blockIdx.x;
  int c = blk % NCHUNK;
  int b = blk / NCHUNK;
  int d0 = threadIdx.x*2;
  float h[G][2];
  #pragma unroll
  for (int le=0; le<G; le++){
    size_t hi = (((size_t)(le*B_BATCH+b))*NCHUNK + c)*D_MODEL + d0;
    h[le][0]=Hinit[hi]; h[le][1]=Hinit[hi+1];
  }
  int s0 = c*CHUNK;
  for (int t=0;t<CHUNK;t++){
    size_t n = (size_t)b*S_SEQ + s0 + t;
    float o0=0.f, o1=0.f;
    #pragma unroll
    for (int le=0;le<G;le++){
      float w = wtok[n*E_EXP + e0 + le];
      size_t idx = (((size_t)(le*B_BATCH+b))*S_SEQ + (size_t)(s0 + t))*D_MODEL + d0;
      unsigned av = *(const unsigned*)(aa+idx);
      unsigned xv = *(const unsigned*)(xs+idx);
      h[le][0] = b2f_lo(av)*h[le][0] + b2f_lo(xv);
      h[le][1] = b2f_hi(av)*h[le][1] + b2f_hi(xv);
      o0 += w*h[le][0];
      o1 += w*h[le][1];
    }
    float* op = out + n*D_MODEL + d0;
    if (G == E_EXP){ op[0]=o0; op[1]=o1; }
    else           { op[0]+=o0; op[1]+=o1; }   // accumulate across expert groups
  }
}

extern "C" void kernel_launch(void* const* d_in, const int* in_sizes, int n_in,
                              void* d_out, int out_size, void* d_ws, size_t ws_size,
                              hipStream_t stream)
{
  const float* x     = (const float*)d_in[0];
  const float* Wg    = (const float*)d_in[1];
  const float* bg    = (const float*)d_in[2];
  const float* Wv    = (const float*)d_in[3];
  const float* bv    = (const float*)d_in[4];
  const float* Wd    = (const float*)d_in[5];
  const float* bd    = (const float*)d_in[6];
  const float* Wgate = (const float*)d_in[7];
  float* out = (float*)d_out;

  const size_t per_e_xs = (size_t)NTOK*D_MODEL*2;            // 32 MiB per bf16 buffer per expert
  const size_t per_e_st = (size_t)B_BATCH*NCHUNK*D_MODEL*4;  // 2 MiB per state buffer per expert
  const size_t wtok_bytes = (size_t)NTOK*E_EXP*4;            // 256 KiB

  // Workspace-adaptive: process G experts per sweep (deterministic per ws_size -> graph-safe)
  int G = 1;
  for (int g = 4; g >= 1; g >>= 1){
    size_t need = wtok_bytes + (size_t)g*(2*per_e_xs + 3*per_e_st);
    if (need <= ws_size){ G = g; break; }
  }
  char* wsb = (char*)d_ws;
  float* wtok = (float*)wsb;                     size_t off = wtok_bytes;
  unsigned short* xs = (unsigned short*)(wsb+off); off += (size_t)G*per_e_xs;
  unsigned short* aa = (unsigned short*)(wsb+off); off += (size_t)G*per_e_xs;
  float* P  = (float*)(wsb+off); off += (size_t)G*per_e_st;
  float* U  = (float*)(wsb+off); off += (size_t)G*per_e_st;
  float* Hi = (float*)(wsb+off);

  hipMemsetAsync(d_out, 0, (size_t)out_size*sizeof(float), stream);
  router_kernel<<<NTOK/4, 256, 0, stream>>>(x, Wgate, wtok);

  for (int e0=0; e0<E_EXP; e0+=G){
    gemm_gv<<<dim3(NTOK/TM, D_MODEL/TN, G), 256, 0, stream>>>(x, Wg, bg, Wv, bv, xs, e0);
    gemm_d <<<dim3(NTOK/TM, D_MODEL/TN, G), 256, 0, stream>>>(x, Wd, bd, aa, e0);
    scan_pass1<<<G*B_BATCH*NCHUNK, 512, 0, stream>>>(xs, aa, P, U);
    scan_pass2<<<G*B_BATCH*D_MODEL/256, 256, 0, stream>>>(P, U, Hi);
    if (G==4)      scan_pass3<4><<<B_BATCH*NCHUNK, 512, 0, stream>>>(xs, aa, Hi, wtok, out, e0);
    else if (G==2) scan_pass3<2><<<B_BATCH*NCHUNK, 512, 0, stream>>>(xs, aa, Hi, wtok, out, e0);
    else           scan_pass3<1><<<B_BATCH*NCHUNK, 512, 0, stream>>>(xs, aa, Hi, wtok, out, e0);
  }
}

// Round 2
// 956.292 us; speedup vs baseline: 5.6602x; 5.6602x over previous
//
#include <hip/hip_runtime.h>

#define E_EXP 4
#define D_MODEL 1024
#define B_BATCH 4
#define S_SEQ 4096
#define NTOK (B_BATCH*S_SEQ)   // 16384
#define CHUNK 32
#define NCHUNK (S_SEQ/CHUNK)   // 128

typedef float f4 __attribute__((ext_vector_type(4)));
typedef float f32x4 __attribute__((ext_vector_type(4)));
typedef short bf16x8 __attribute__((ext_vector_type(8)));

__device__ __forceinline__ unsigned short f2b(float f){
  union{float f;unsigned u;}v; v.f=f;
  unsigned r = v.u + 0x7fffu + ((v.u>>16)&1u);
  return (unsigned short)(r>>16);
}
__device__ __forceinline__ float b2f_us(unsigned short v){ union{unsigned u;float f;}x; x.u=((unsigned)v)<<16; return x.f; }
__device__ __forceinline__ float b2f_lo(unsigned v){ union{unsigned u;float f;}x; x.u=v<<16; return x.f; }
__device__ __forceinline__ float b2f_hi(unsigned v){ union{unsigned u;float f;}x; x.u=v&0xffff0000u; return x.f; }

__device__ __forceinline__ void gload_lds16(const void* g, void* l){
  __builtin_amdgcn_global_load_lds(
      (const __attribute__((address_space(1))) void*)g,
      (__attribute__((address_space(3))) void*)l, 16, 0, 0);
}

// ---------------- fp32 -> bf16 conversion ----------------
__global__ __launch_bounds__(256) void cvt_bf16(const float* __restrict__ src,
                                                unsigned short* __restrict__ dst)
{
  size_t i = ((size_t)blockIdx.x*256 + threadIdx.x)*4;
  f4 v = *(const f4*)(src + i);
  ushort4 o; o.x=f2b(v[0]); o.y=f2b(v[1]); o.z=f2b(v[2]); o.w=f2b(v[3]);
  *(ushort4*)(dst + i) = o;
}

// ---------------- router: top-2 softmax gate weights per token ----------------
__global__ __launch_bounds__(256) void router_kernel(
    const float* __restrict__ x, const float* __restrict__ Wgate,
    float* __restrict__ wtok)
{
  int gtid = blockIdx.x*256 + threadIdx.x;
  int tok  = gtid >> 6;
  int lane = threadIdx.x & 63;
  const float* xr = x + (size_t)tok * D_MODEL;
  float acc0=0.f,acc1=0.f,acc2=0.f,acc3=0.f;
  for (int k=lane;k<D_MODEL;k+=64){
    float xv = xr[k];
    acc0 += xv*Wgate[0*D_MODEL+k];
    acc1 += xv*Wgate[1*D_MODEL+k];
    acc2 += xv*Wgate[2*D_MODEL+k];
    acc3 += xv*Wgate[3*D_MODEL+k];
  }
  #pragma unroll
  for (int off=32;off>0;off>>=1){
    acc0 += __shfl_down(acc0,off);
    acc1 += __shfl_down(acc1,off);
    acc2 += __shfl_down(acc2,off);
    acc3 += __shfl_down(acc3,off);
  }
  if (lane==0){
    float l[4]={acc0,acc1,acc2,acc3};
    int i1=0;
    #pragma unroll
    for(int e=1;e<4;e++) if (l[e]>l[i1]) i1=e;
    int i2=-1;
    #pragma unroll
    for(int e=0;e<4;e++){ if(e==i1) continue; if(i2<0||l[e]>l[i2]) i2=e; }
    float ex = __expf(l[i2]-l[i1]);
    float w1 = 1.f/(1.f+ex);
    float w2 = ex/(1.f+ex);
    float w[4]={0.f,0.f,0.f,0.f};
    w[i1]=w1; w[i2]=w2;
    float* wp = wtok + (size_t)tok*E_EXP;
    wp[0]=w[0]; wp[1]=w[1]; wp[2]=w[2]; wp[3]=w[3];
  }
}

// ---------------- bf16 MFMA GEMM (m97 recipe), fused epilogues ----------------
// C[m,n] = sum_k A[m,k]*W[n,k] + bias[n]   (NT, both row-major k-contiguous)
// EPI 0: dst = bf16(C)                      (raw g, lands in aa buffer)
// EPI 1: dst = bf16( sigmoid(gsrc)*tanh(C) )  (xs)
// EPI 2: dst = bf16( 0.001 + 0.998*sigmoid(C) ) (decay a, overwrites aa)
#define BM 128
#define BN 128
#define BK 32

template<int EPI>
__global__ __launch_bounds__(256) void gemm_bf16(
    const unsigned short* __restrict__ A,     // xbf [NTOK][D]
    const unsigned short* __restrict__ W,     // Wbf [G][D][D] (sweep-local)
    const float* __restrict__ bias,           // fp32 [E][D], absolute-e indexed
    const unsigned short* __restrict__ gsrc,  // EPI==1: g bf16 (aa buffer)
    unsigned short* __restrict__ dst,
    int e0)
{
  __shared__ unsigned short sA[BM*BK];   // 8 KB
  __shared__ unsigned short sB[BN*BK];   // 8 KB
  int le = blockIdx.z;
  int mbase = blockIdx.x*BM, nbase = blockIdx.y*BN;
  int tid  = threadIdx.x;
  int wave = tid>>6, lane = tid&63;
  int wm = wave>>1, wn = wave&1;

  const unsigned short* We = W + (size_t)le*D_MODEL*D_MODEL;

  // staging: each wave stages rows [wave*32, wave*32+32) of both tiles,
  // 2 instrs of 16 rows each; lane -> row wave*32+(lane>>2)(+16), col (lane&3)*8
  int srow = wave*32 + (lane>>2);
  int scol = (lane&3)*8;
  const unsigned short* gA0 = A  + (size_t)(mbase+srow)*D_MODEL + scol;
  const unsigned short* gA1 = gA0 + (size_t)16*D_MODEL;
  const unsigned short* gB0 = We + (size_t)(nbase+srow)*D_MODEL + scol;
  const unsigned short* gB1 = gB0 + (size_t)16*D_MODEL;
  unsigned short* lA0 = &sA[(wave*32)*BK];
  unsigned short* lA1 = &sA[(wave*32+16)*BK];
  unsigned short* lB0 = &sB[(wave*32)*BK];
  unsigned short* lB1 = &sB[(wave*32+16)*BK];

  f32x4 acc[4][4];
  #pragma unroll
  for (int i=0;i<4;i++)
    #pragma unroll
    for (int j=0;j<4;j++) acc[i][j] = 0;

  int arow = wm*64 + (lane&15);     // + mi*16
  int brow = wn*64 + (lane&15);     // + ni*16
  int kfr  = (lane>>4)*8;

  for (int k0=0; k0<D_MODEL; k0+=BK){
    gload_lds16(gA0 + k0, lA0);
    gload_lds16(gA1 + k0, lA1);
    gload_lds16(gB0 + k0, lB0);
    gload_lds16(gB1 + k0, lB1);
    __syncthreads();
    bf16x8 af[4], bfv[4];
    #pragma unroll
    for (int mi=0;mi<4;mi++) af[mi]  = *(const bf16x8*)&sA[(arow + mi*16)*BK + kfr];
    #pragma unroll
    for (int ni=0;ni<4;ni++) bfv[ni] = *(const bf16x8*)&sB[(brow + ni*16)*BK + kfr];
    #pragma unroll
    for (int mi=0;mi<4;mi++)
      #pragma unroll
      for (int ni=0;ni<4;ni++)
        acc[mi][ni] = __builtin_amdgcn_mfma_f32_16x16x32_bf16(af[mi], bfv[ni], acc[mi][ni], 0, 0, 0);
    __syncthreads();
  }

  // epilogue: C/D layout col=lane&15, row=(lane>>4)*4+r  [m89-verified]
  const float* be = bias + (size_t)(e0+le)*D_MODEL;
  int me = mbase + wm*64;
  int ne = nbase + wn*64;
  #pragma unroll
  for (int mi=0;mi<4;mi++){
    #pragma unroll
    for (int r=0;r<4;r++){
      int m = me + mi*16 + (lane>>4)*4 + r;
      size_t rowoff = ((size_t)le*NTOK + m)*D_MODEL;
      #pragma unroll
      for (int ni=0;ni<4;ni++){
        int n = ne + ni*16 + (lane&15);
        float val = acc[mi][ni][r] + be[n];
        float res;
        if (EPI==0){
          res = val;
        } else if (EPI==1){
          float g  = b2f_us(gsrc[rowoff+n]);
          float sg = 1.f/(1.f+__expf(-g));
          float th = 1.f - 2.f/(__expf(2.f*val)+1.f);
          res = sg*th;
        } else {
          res = 0.001f + 0.998f/(1.f+__expf(-val));
        }
        dst[rowoff+n] = f2b(res);
      }
    }
  }
}

// ---------------- chunked scan pass 1: local scan per chunk -> (P, U) ----------------
__global__ __launch_bounds__(512) void scan_pass1(
    const unsigned short* __restrict__ xs, const unsigned short* __restrict__ aa,
    float* __restrict__ P, float* __restrict__ U)
{
  int blk = blockIdx.x;
  int c  = blk % NCHUNK;
  int b  = (blk / NCHUNK) % B_BATCH;
  int le = blk / (NCHUNK*B_BATCH);
  int d0 = threadIdx.x*2;
  size_t base = (((size_t)(le*B_BATCH + b))*S_SEQ + (size_t)c*CHUNK)*D_MODEL + d0;
  float h0=0.f,h1=0.f,p0=1.f,p1=1.f;
  #pragma unroll 4
  for (int t=0;t<CHUNK;t++){
    unsigned av = *(const unsigned*)(aa + base);
    unsigned xv = *(const unsigned*)(xs + base);
    float a0=b2f_lo(av), a1=b2f_hi(av);
    float x0=b2f_lo(xv), x1=b2f_hi(xv);
    h0 = a0*h0 + x0; h1 = a1*h1 + x1;
    p0 *= a0; p1 *= a1;
    base += D_MODEL;
  }
  size_t sidx = (((size_t)(le*B_BATCH + b))*NCHUNK + c)*D_MODEL + d0;
  P[sidx]=p0; P[sidx+1]=p1;
  U[sidx]=h0; U[sidx+1]=h1;
}

// ---------------- pass 2: sequential combine over chunks -> Hinit per chunk ----------------
__global__ __launch_bounds__(256) void scan_pass2(
    const float* __restrict__ P, const float* __restrict__ U, float* __restrict__ Hinit)
{
  int ch = blockIdx.x*256 + threadIdx.x;
  int d  = ch & (D_MODEL-1);
  int eb = ch >> 10;
  size_t base = (size_t)eb*NCHUNK*D_MODEL + d;
  float H=0.f;
  for (int c=0;c<NCHUNK;c++){
    size_t idx = base + (size_t)c*D_MODEL;
    Hinit[idx] = H;
    H = P[idx]*H + U[idx];
  }
}

// ---------------- pass 3: re-scan + fused top-2 weighted combine ----------------
template<int G>
__global__ __launch_bounds__(512) void scan_pass3(
    const unsigned short* __restrict__ xs, const unsigned short* __restrict__ aa,
    const float* __restrict__ Hinit, const float* __restrict__ wtok,
    float* __restrict__ out, int e0)
{
  int blk = blockIdx.x;
  int c = blk % NCHUNK;
  int b = blk / NCHUNK;
  int d0 = threadIdx.x*2;
  float h[G][2];
  #pragma unroll
  for (int le=0; le<G; le++){
    size_t hi = (((size_t)(le*B_BATCH+b))*NCHUNK + c)*D_MODEL + d0;
    h[le][0]=Hinit[hi]; h[le][1]=Hinit[hi+1];
  }
  int s0 = c*CHUNK;
  for (int t=0;t<CHUNK;t++){
    size_t n = (size_t)b*S_SEQ + s0 + t;
    float o0=0.f, o1=0.f;
    #pragma unroll
    for (int le=0;le<G;le++){
      float w = wtok[n*E_EXP + e0 + le];
      size_t idx = (((size_t)(le*B_BATCH+b))*S_SEQ + (size_t)(s0 + t))*D_MODEL + d0;
      unsigned av = *(const unsigned*)(aa+idx);
      unsigned xv = *(const unsigned*)(xs+idx);
      h[le][0] = b2f_lo(av)*h[le][0] + b2f_lo(xv);
      h[le][1] = b2f_hi(av)*h[le][1] + b2f_hi(xv);
      o0 += w*h[le][0];
      o1 += w*h[le][1];
    }
    float* op = out + n*D_MODEL + d0;
    if (G == E_EXP){ op[0]=o0; op[1]=o1; }
    else           { op[0]+=o0; op[1]+=o1; }
  }
}

extern "C" void kernel_launch(void* const* d_in, const int* in_sizes, int n_in,
                              void* d_out, int out_size, void* d_ws, size_t ws_size,
                              hipStream_t stream)
{
  const float* x     = (const float*)d_in[0];
  const float* Wg    = (const float*)d_in[1];
  const float* bg    = (const float*)d_in[2];
  const float* Wv    = (const float*)d_in[3];
  const float* bv    = (const float*)d_in[4];
  const float* Wd    = (const float*)d_in[5];
  const float* bd    = (const float*)d_in[6];
  const float* Wgate = (const float*)d_in[7];
  float* out = (float*)d_out;

  const size_t DD       = (size_t)D_MODEL*D_MODEL;          // 1M elements
  const size_t wtok_b   = (size_t)NTOK*E_EXP*4;             // 256 KiB
  const size_t xbf_b    = (size_t)NTOK*D_MODEL*2;           // 32 MiB
  const size_t w_per_e  = DD*2;                             // 2 MiB
  const size_t xs_per_e = (size_t)NTOK*D_MODEL*2;           // 32 MiB
  const size_t st_per_e = (size_t)B_BATCH*NCHUNK*D_MODEL*4; // 2 MiB

  // adaptive expert-group size (deterministic per ws_size -> graph-safe)
  int G = 1;
  for (int g = 4; g >= 1; g >>= 1){
    size_t need = wtok_b + xbf_b + (size_t)g*(3*w_per_e + 2*xs_per_e + 3*st_per_e);
    if (need <= ws_size){ G = g; break; }
  }

  char* wsb = (char*)d_ws;
  size_t off = 0;
  float*          wtok = (float*)(wsb+off);          off += wtok_b;
  unsigned short* xbf  = (unsigned short*)(wsb+off); off += xbf_b;
  unsigned short* Wgbf = (unsigned short*)(wsb+off); off += (size_t)G*w_per_e;
  unsigned short* Wvbf = (unsigned short*)(wsb+off); off += (size_t)G*w_per_e;
  unsigned short* Wdbf = (unsigned short*)(wsb+off); off += (size_t)G*w_per_e;
  unsigned short* xs   = (unsigned short*)(wsb+off); off += (size_t)G*xs_per_e;
  unsigned short* aa   = (unsigned short*)(wsb+off); off += (size_t)G*xs_per_e;  // also holds g temporarily
  float*          P    = (float*)(wsb+off);          off += (size_t)G*st_per_e;
  float*          U    = (float*)(wsb+off);          off += (size_t)G*st_per_e;
  float*          Hi   = (float*)(wsb+off);

  hipMemsetAsync(d_out, 0, (size_t)out_size*sizeof(float), stream);

  // x -> bf16 (once), router
  cvt_bf16<<<(unsigned)((size_t)NTOK*D_MODEL/1024), 256, 0, stream>>>(x, xbf);
  router_kernel<<<NTOK/4, 256, 0, stream>>>(x, Wgate, wtok);

  for (int e0=0; e0<E_EXP; e0+=G){
    // weight slices -> bf16
    cvt_bf16<<<(unsigned)((size_t)G*DD/1024), 256, 0, stream>>>(Wg + (size_t)e0*DD, Wgbf);
    cvt_bf16<<<(unsigned)((size_t)G*DD/1024), 256, 0, stream>>>(Wv + (size_t)e0*DD, Wvbf);
    cvt_bf16<<<(unsigned)((size_t)G*DD/1024), 256, 0, stream>>>(Wd + (size_t)e0*DD, Wdbf);

    dim3 gg(NTOK/BM, D_MODEL/BN, G);
    // g -> aa (bf16 raw)
    gemm_bf16<0><<<gg, 256, 0, stream>>>(xbf, Wgbf, bg, nullptr, aa, e0);
    // v; epilogue reads g from aa, writes xs
    gemm_bf16<1><<<gg, 256, 0, stream>>>(xbf, Wvbf, bv, aa, xs, e0);
    // d; overwrites aa with decay a
    gemm_bf16<2><<<gg, 256, 0, stream>>>(xbf, Wdbf, bd, nullptr, aa, e0);

    scan_pass1<<<G*B_BATCH*NCHUNK, 512, 0, stream>>>(xs, aa, P, U);
    scan_pass2<<<G*B_BATCH*D_MODEL/256, 256, 0, stream>>>(P, U, Hi);
    if (G==4)      scan_pass3<4><<<B_BATCH*NCHUNK, 512, 0, stream>>>(xs, aa, Hi, wtok, out, e0);
    else if (G==2) scan_pass3<2><<<B_BATCH*NCHUNK, 512, 0, stream>>>(xs, aa, Hi, wtok, out, e0);
    else           scan_pass3<1><<<B_BATCH*NCHUNK, 512, 0, stream>>>(xs, aa, Hi, wtok, out, e0);
  }
}